// Round 4
// baseline (51.680 us; speedup 1.0000x reference)
//
#include <hip/hip_runtime.h>

// out[b,s,d] = relu(x[b,s] * W[s,d] + bias[s,d])
// B=256, S=512, D=512 (fp32). Pure write-bandwidth kernel: 268 MB out.
//
// Structure: t = 0..524287; d4 = t&127, bs0 = t>>7. Per iteration bs += 4096
// (b += 8), s/d4 fixed -> W/bias loaded once per thread.
//
// Round-2 lesson: nontemporal stores regress (50->65us); keep cached stores.
// Round-4 theory: vmcnt completion is in-order, so interleaved
// {load x, store} serializes each iteration on store-acks. bs0 is
// wave-uniform -> readfirstlane + uniform pointer => s_load_dword (lgkmcnt,
// scalar path) with immediate offsets, fully decoupled from the store queue.

typedef float __attribute__((ext_vector_type(4))) floatx4;

constexpr int D4      = 128;        // 512/4
constexpr int THREADS = 2048 * 256; // 524288
constexpr int ITERS   = 32;         // 16777216 float4 / 524288

__global__ void __launch_bounds__(256) od2d_kernel(
    const float*   __restrict__ x,    // [B*S]
    const floatx4* __restrict__ W4,   // [S*D4]
    const floatx4* __restrict__ b4,   // [S*D4]
    floatx4*       __restrict__ o4)   // [B*S*D4]
{
    const unsigned t   = blockIdx.x * 256 + threadIdx.x;  // 0..524287
    const unsigned d4  = t & (D4 - 1);
    const unsigned bs0 = t >> 7;                // wave-uniform (64 lanes share it)
    const unsigned s   = bs0 & 511;
    const unsigned wi  = (s << 7) + d4;

    const floatx4 w  = W4[wi];
    const floatx4 bb = b4[wi];

    // Uniform x pointer -> scalar loads (s_load_dword, imm offsets 0..496KB).
    const float* xp = x + __builtin_amdgcn_readfirstlane(bs0);
    float xv[ITERS];
    #pragma unroll
    for (int k = 0; k < ITERS; ++k)
        xv[k] = xp[4096u * k];       // static index -> SGPR-resident after unroll

    unsigned i = t;
    #pragma unroll
    for (int k = 0; k < ITERS; ++k) {
        floatx4 r;
        r.x = fmaxf(fmaf(xv[k], w.x, bb.x), 0.0f);
        r.y = fmaxf(fmaf(xv[k], w.y, bb.y), 0.0f);
        r.z = fmaxf(fmaf(xv[k], w.z, bb.z), 0.0f);
        r.w = fmaxf(fmaf(xv[k], w.w, bb.w), 0.0f);
        o4[i] = r;
        i += THREADS;
    }
}

extern "C" void kernel_launch(void* const* d_in, const int* in_sizes, int n_in,
                              void* d_out, int out_size, void* d_ws, size_t ws_size,
                              hipStream_t stream) {
    const float*   x  = (const float*)d_in[0];
    const floatx4* W4 = (const floatx4*)d_in[1];
    const floatx4* b4 = (const floatx4*)d_in[2];
    floatx4* o4 = (floatx4*)d_out;

    od2d_kernel<<<2048, 256, 0, stream>>>(x, W4, b4, o4);
}